// Round 1
// 572.655 us; speedup vs baseline: 1.1471x; 1.1471x over previous
//
#include <hip/hip_runtime.h>
#include <hip/hip_bf16.h>
#include <cstdint>
#include <cstddef>

// MHA forward. b=4, n=2048, d_model=1024, heads=16, dk=64, causal.
// Inputs: float32 (confirmed R1-R5). Output: float32 (confirmed R5 green).
// Compute: bf16 MFMA, fp32 accumulate; intermediates bf16 row-major [b*n,1024].
//
// R7: flash_attn was latency-bound (Occupancy 14%, MfmaUtil 4.8%, all pipes idle).
//   - q-tile 128 -> 64 rows (wave owns 16 rows): grid 1024 -> 2048 blocks,
//     LDS 36 KB -> 24 KB (6 blocks/CU LDS-limit vs 4).
//   - XOR-swizzled LDS (stride 72 -> 64, col ^= (row&7)<<3 write+read): the old
//     stride-72 rows aliased to 8 banks -> 8-way conflict on every ds_read_b128.
//   - T14 async-stage: next K/V tile global->regs issued right after the stage
//     barrier; LDS write at top of next iter. Latency hides under QK/softmax/PV.
//   - Global heavy-first dispatch: bh on blockIdx.x, heaviest q-tile first on y.
// GEMMs unchanged this round.

typedef __bf16 bf16_t;
typedef bf16_t bf16x8 __attribute__((ext_vector_type(8)));
typedef float floatx4 __attribute__((ext_vector_type(4)));

#define MFMA(a, b, c) __builtin_amdgcn_mfma_f32_16x16x32_bf16((a), (b), (c), 0, 0, 0)
#define NEG_BIG (-30000.0f)  // exp2-domain sentinel; v_exp_f32 underflows to 0

static __device__ __forceinline__ bf16_t f2bf(float x) { return (bf16_t)x; }

static __device__ __forceinline__ bf16x8 cvt8(const float* p) {
  const floatx4 a = *(const floatx4*)p;
  const floatx4 b = *(const floatx4*)(p + 4);
  bf16x8 r;
  r[0] = (bf16_t)a[0]; r[1] = (bf16_t)a[1]; r[2] = (bf16_t)a[2]; r[3] = (bf16_t)a[3];
  r[4] = (bf16_t)b[0]; r[5] = (bf16_t)b[1]; r[6] = (bf16_t)b[2]; r[7] = (bf16_t)b[3];
  return r;
}

// f32-vs-bf16 sniffer on w_q's first 64 uint16s (validated: picks f32 path).
__global__ void detect_dtype(const unsigned short* __restrict__ w,
                             int* __restrict__ flag) {
  const unsigned short u = w[threadIdx.x];
  const bool big = (u & 0x7F80u) >= 0x3F80u;
  const unsigned long long m = __ballot(big);
  if (threadIdx.x == 0) *flag = (m != 0ull) ? 1 : 0;
}

// ---------------------------------------------------------------------------
// C[M,1024] = A[M,1024] @ W[1024,1024]^T, row-major, OutT out (bf16 or f32).
// ADT: 0 = A external (f32/bf16 per flag), 1 = A internal bf16.
// Tile 128x128, BK=32, 4 waves (2x2), 4x4 mfma_16x16x32 per wave.
// LDS stride 40 (16B-aligned rows, <=2-way bank aliasing = free).   [R5 green]
// ---------------------------------------------------------------------------
template <int ADT, typename OutT>
__global__ __launch_bounds__(256, 2)
void gemm_bt(const void* __restrict__ Av, const void* __restrict__ Wv,
             OutT* __restrict__ C, const int* __restrict__ flag)
{
  const int K = 1024;
  __shared__ __align__(16) bf16_t sA[128 * 40];
  __shared__ __align__(16) bf16_t sB[128 * 40];
  const int tid  = threadIdx.x;
  const int wave = tid >> 6;
  const int lane = tid & 63;
  const int wm = wave >> 1, wn = wave & 1;
  const int bm = blockIdx.y * 128, bn = blockIdx.x * 128;
  const int quad = lane >> 4, r16 = lane & 15;
  const int f32in = *flag;

  floatx4 acc[4][4];
  #pragma unroll
  for (int i = 0; i < 4; ++i)
    #pragma unroll
    for (int j = 0; j < 4; ++j) acc[i][j] = {0.f, 0.f, 0.f, 0.f};

  const int srow = tid >> 2;       // 0..63
  const int scol = (tid & 3) * 8;  // 0,8,16,24
  const int ar0 = bm + srow, ar1 = bm + srow + 64;
  const int wr0 = bn + srow, wr1 = bn + srow + 64;

  for (int k0 = 0; k0 < K; k0 += 32) {
    bf16x8 va0, va1, vb0, vb1;
    if (ADT == 0 && f32in) {
      const float* Af = (const float*)Av;
      va0 = cvt8(Af + (size_t)ar0 * K + k0 + scol);
      va1 = cvt8(Af + (size_t)ar1 * K + k0 + scol);
    } else {
      const bf16_t* Ab = (const bf16_t*)Av;
      va0 = *(const bf16x8*)(Ab + (size_t)ar0 * K + k0 + scol);
      va1 = *(const bf16x8*)(Ab + (size_t)ar1 * K + k0 + scol);
    }
    if (f32in) {
      const float* Wf = (const float*)Wv;
      vb0 = cvt8(Wf + (size_t)wr0 * K + k0 + scol);
      vb1 = cvt8(Wf + (size_t)wr1 * K + k0 + scol);
    } else {
      const bf16_t* Wb = (const bf16_t*)Wv;
      vb0 = *(const bf16x8*)(Wb + (size_t)wr0 * K + k0 + scol);
      vb1 = *(const bf16x8*)(Wb + (size_t)wr1 * K + k0 + scol);
    }
    *(bf16x8*)&sA[srow * 40 + scol]        = va0;
    *(bf16x8*)&sA[(srow + 64) * 40 + scol] = va1;
    *(bf16x8*)&sB[srow * 40 + scol]        = vb0;
    *(bf16x8*)&sB[(srow + 64) * 40 + scol] = vb1;
    __syncthreads();

    bf16x8 af[4], bv[4];
    #pragma unroll
    for (int mi = 0; mi < 4; ++mi)
      af[mi] = *(const bf16x8*)&sA[(wm * 64 + mi * 16 + r16) * 40 + quad * 8];
    #pragma unroll
    for (int ni = 0; ni < 4; ++ni)
      bv[ni] = *(const bf16x8*)&sB[(wn * 64 + ni * 16 + r16) * 40 + quad * 8];
    #pragma unroll
    for (int mi = 0; mi < 4; ++mi)
      #pragma unroll
      for (int ni = 0; ni < 4; ++ni)
        acc[mi][ni] = MFMA(af[mi], bv[ni], acc[mi][ni]);
    __syncthreads();
  }

  #pragma unroll
  for (int mi = 0; mi < 4; ++mi)
    #pragma unroll
    for (int ni = 0; ni < 4; ++ni)
      #pragma unroll
      for (int r = 0; r < 4; ++r) {
        const int row = bm + wm * 64 + mi * 16 + quad * 4 + r;
        const int col = bn + wn * 64 + ni * 16 + r16;
        C[(size_t)row * 1024 + col] = (OutT)acc[mi][ni][r];
      }
}

// ---------------------------------------------------------------------------
// Causal MFMA flash attention over row-major [8192][1024] bf16 q/k/v, head =
// 64-col slice. Block = 256 threads (4 waves): one (bh, 64-row q-tile).
// Wave w owns S/O rows [w*16, w*16+16). BKV = 64. Finite mask sentinels.
// All LDS tiles [64][64] XOR-swizzled: idx = row*64 + (col ^ ((row&7)<<3)),
// applied identically on write and read -> ds_read_b128 conflict-free.
// Next K/V tile prefetched into regs after the stage barrier (T14).
// Output in-place over q rows (block-private).
// ---------------------------------------------------------------------------
__global__ __launch_bounds__(256, 4)
void flash_attn(bf16_t* qio, const bf16_t* __restrict__ kh,
                const bf16_t* __restrict__ vh)
{
  __shared__ __align__(16) bf16_t sK[64 * 64];    // [kv][d]  8 KB, swizzled
  __shared__ __align__(16) bf16_t sVt[64 * 64];   // [d][kv]  8 KB, swizzled
  __shared__ __align__(16) bf16_t sP[64 * 64];    // [q][kv]  8 KB, swizzled
  const int tid  = threadIdx.x;
  const int wave = tid >> 6;
  const int lane = tid & 63;
  const int quad = lane >> 4, r16 = lane & 15;
  const int b = blockIdx.x >> 4, h = blockIdx.x & 15;
  const int q0 = (int)(gridDim.y - 1 - blockIdx.y) * 64;  // heavy tiles first
  const size_t hb = ((size_t)b * 2048) * 1024 + (size_t)h * 64;
  const int swl = (r16 & 7) << 3;  // read-side XOR for r16-indexed rows

  // Q fragments (reused across all kv tiles): rows q0 + wave*16 + r16
  bf16x8 qf[2];
  #pragma unroll
  for (int ks = 0; ks < 2; ++ks)
    qf[ks] = *(const bf16x8*)(qio + hb +
        (size_t)(q0 + wave * 16 + r16) * 1024 + ks * 32 + quad * 8);

  floatx4 o[4];
  float mrow[4], lrow[4];
  #pragma unroll
  for (int nd = 0; nd < 4; ++nd) o[nd] = {0.f, 0.f, 0.f, 0.f};
  #pragma unroll
  for (int r = 0; r < 4; ++r) { mrow[r] = NEG_BIG; lrow[r] = 0.f; }

  const float sc = 0.125f * 1.44269504089f;  // 1/sqrt(64) * log2(e)
  const int kend = q0 + 64;

  // staging decomposition (per thread, per j): K chunk (row c>>3, col (c&7)*8)
  // and V chunk (row c&63, col (c>>6)*8), c = j*256 + tid.
  bf16x8 kst[2], vst[2];
  #pragma unroll
  for (int j = 0; j < 2; ++j) {
    const int c = j * 256 + tid;
    kst[j] = *(const bf16x8*)(kh + hb + (size_t)(c >> 3) * 1024 + (c & 7) * 8);
    vst[j] = *(const bf16x8*)(vh + hb + (size_t)(c & 63) * 1024 + (c >> 6) * 8);
  }

  for (int kv0 = 0; kv0 < kend; kv0 += 64) {
    // ---- write staged regs -> LDS (swizzled) ----
    #pragma unroll
    for (int j = 0; j < 2; ++j) {
      const int c = j * 256 + tid;
      const int krow = c >> 3, kcol = (c & 7) * 8;
      *(bf16x8*)&sK[krow * 64 + (kcol ^ ((krow & 7) << 3))] = kst[j];
      const int vkv = c & 63, vd = (c >> 6) * 8;
      #pragma unroll
      for (int e = 0; e < 8; ++e)        // row = vd+e, (row&7)==e since vd%8==0
        sVt[(vd + e) * 64 + (vkv ^ (e << 3))] = vst[j][e];
    }
    __syncthreads();

    // ---- prefetch next tile into regs; latency hides under QK/softmax/PV ----
    if (kv0 + 64 < kend) {
      #pragma unroll
      for (int j = 0; j < 2; ++j) {
        const int c = j * 256 + tid;
        kst[j] = *(const bf16x8*)(kh + hb + (size_t)(kv0 + 64 + (c >> 3)) * 1024 + (c & 7) * 8);
        vst[j] = *(const bf16x8*)(vh + hb + (size_t)(kv0 + 64 + (c & 63)) * 1024 + (c >> 6) * 8);
      }
    }

    // ---- S = Q K^T ----
    floatx4 s[4];
    #pragma unroll
    for (int nk = 0; nk < 4; ++nk) s[nk] = {0.f, 0.f, 0.f, 0.f};
    #pragma unroll
    for (int ks = 0; ks < 2; ++ks) {
      bf16x8 bk[4];
      #pragma unroll
      for (int nk = 0; nk < 4; ++nk)
        bk[nk] = *(const bf16x8*)&sK[(nk * 16 + r16) * 64 + ((ks * 32 + quad * 8) ^ swl)];
      #pragma unroll
      for (int nk = 0; nk < 4; ++nk)
        s[nk] = MFMA(qf[ks], bk[nk], s[nk]);
    }

    // ---- scale + causal mask (exp2 domain, finite sentinel) ----
    const int rowb = q0 + wave * 16 + quad * 4;
    const bool domask = (kv0 + 63 > rowb);
    #pragma unroll
    for (int nk = 0; nk < 4; ++nk) {
      const int col = kv0 + nk * 16 + r16;
      #pragma unroll
      for (int r = 0; r < 4; ++r) {
        float t = s[nk][r] * sc;
        if (domask && col > rowb + r) t = NEG_BIG;
        s[nk][r] = t;
      }
    }

    // ---- online softmax; P -> LDS in A-operand layout (swizzled) ----
    #pragma unroll
    for (int r = 0; r < 4; ++r) {
      float mx = fmaxf(fmaxf(s[0][r], s[1][r]), fmaxf(s[2][r], s[3][r]));
      #pragma unroll
      for (int off = 8; off >= 1; off >>= 1)
        mx = fmaxf(mx, __shfl_xor(mx, off, 64));
      const float mnew  = fmaxf(mrow[r], mx);
      const float alpha = exp2f(mrow[r] - mnew);
      mrow[r] = mnew;
      float ls = 0.f;
      const int prow = wave * 16 + quad * 4 + r;
      const int psw  = (prow & 7) << 3;
      #pragma unroll
      for (int nk = 0; nk < 4; ++nk) {
        const bf16_t pb = f2bf(exp2f(s[nk][r] - mnew));
        ls += (float)pb;  // denominator matches the bf16 P used in PV
        sP[prow * 64 + ((nk * 16 + r16) ^ psw)] = pb;
      }
      #pragma unroll
      for (int off = 8; off >= 1; off >>= 1)
        ls += __shfl_xor(ls, off, 64);
      lrow[r] = lrow[r] * alpha + ls;
      #pragma unroll
      for (int nd = 0; nd < 4; ++nd) o[nd][r] *= alpha;
    }
    __syncthreads();  // sP visible across lanes

    // ---- O += P V ----
    #pragma unroll
    for (int ks = 0; ks < 2; ++ks) {
      const int cb = (ks * 32 + quad * 8) ^ swl;
      const bf16x8 pa = *(const bf16x8*)&sP[(wave * 16 + r16) * 64 + cb];
      bf16x8 vb[4];
      #pragma unroll
      for (int nd = 0; nd < 4; ++nd)
        vb[nd] = *(const bf16x8*)&sVt[(nd * 16 + r16) * 64 + cb];
      #pragma unroll
      for (int nd = 0; nd < 4; ++nd)
        o[nd] = MFMA(pa, vb[nd], o[nd]);
    }
    __syncthreads();  // protect sK/sVt/sP for next iteration
  }

  // ---- normalize + store (in-place over q rows; block-private) ----
  #pragma unroll
  for (int r = 0; r < 4; ++r) {
    const float inv = 1.f / lrow[r];
    const int row = q0 + wave * 16 + quad * 4 + r;
    #pragma unroll
    for (int nd = 0; nd < 4; ++nd)
      qio[hb + (size_t)row * 1024 + nd * 16 + r16] = f2bf(o[nd][r] * inv);
  }
}

// ---------------------------------------------------------------------------
extern "C" void kernel_launch(void* const* d_in, const int* in_sizes, int n_in,
                              void* d_out, int out_size, void* d_ws, size_t ws_size,
                              hipStream_t stream) {
  (void)in_sizes; (void)n_in; (void)out_size; (void)ws_size;
  const size_t TSZ = (size_t)8192 * 1024;
  int*    flag = (int*)d_ws;
  bf16_t* qws  = (bf16_t*)((char*)d_ws + 16);
  bf16_t* kws  = qws + TSZ;
  bf16_t* vws  = (bf16_t*)d_out;  // bf16 v parked in f32 out buffer

  detect_dtype<<<1, 64, 0, stream>>>((const unsigned short*)d_in[3], flag);

  const dim3 gg(8, 64);  // (N/128, M/128)
  gemm_bt<0, bf16_t><<<gg, 256, 0, stream>>>(d_in[0], d_in[3], qws, flag);
  gemm_bt<0, bf16_t><<<gg, 256, 0, stream>>>(d_in[1], d_in[4], kws, flag);
  gemm_bt<0, bf16_t><<<gg, 256, 0, stream>>>(d_in[2], d_in[5], vws, flag);
  flash_attn<<<dim3(64, 32), 256, 0, stream>>>(qws, kws, vws);
  gemm_bt<1, float><<<gg, 256, 0, stream>>>(qws, d_in[6], (float*)d_out, flag);
}

// Round 2
// 498.329 us; speedup vs baseline: 1.3182x; 1.1492x over previous
//
#include <hip/hip_runtime.h>
#include <hip/hip_bf16.h>
#include <cstdint>
#include <cstddef>

// MHA forward. b=4, n=2048, d_model=1024, heads=16, dk=64, causal.
// Inputs: float32 (confirmed R1-R5). Output: float32 (confirmed R5 green).
// Compute: bf16 MFMA, fp32 accumulate; intermediates bf16 row-major [b*n,1024].
//
// R8: GEMMs were the bigger half (4 x ~89 us = 356 us vs flash 217 us) at only
// 193 TF each. Cause: zero load-latency hiding (load->cvt->write->barrier per
// k-step, 32 steps x ~700 cy latency on the critical path) + 2 barriers/step.
//   - double-buffered LDS: ONE barrier per k-step (hazard-free: a wave reaching
//     iter t+1's write passed iter t's barrier, which orders it after every
//     wave's iter t-1 compute on the same buffer).
//   - T14 register prefetch: next k-tile global loads issued right AFTER the
//     barrier (issuing before would be drained by __syncthreads' vmcnt(0));
//     raw f32 held in regs, cvt to bf16 deferred to LDS-write time so the
//     vmcnt wait lands one full compute-phase after issue.
//   - runtime dtype flag hoisted out of the k-loop via template<AF32,WF32>
//     so f32/bf16 staging register sets are never both live.
// flash_attn unchanged this round (R7: swizzle+prefetch, 305->217 us).

typedef __bf16 bf16_t;
typedef bf16_t bf16x8 __attribute__((ext_vector_type(8)));
typedef float floatx4 __attribute__((ext_vector_type(4)));

#define MFMA(a, b, c) __builtin_amdgcn_mfma_f32_16x16x32_bf16((a), (b), (c), 0, 0, 0)
#define NEG_BIG (-30000.0f)  // exp2-domain sentinel; v_exp_f32 underflows to 0

static __device__ __forceinline__ bf16_t f2bf(float x) { return (bf16_t)x; }

static __device__ __forceinline__ bf16x8 cvt8p(const floatx4 a, const floatx4 b) {
  bf16x8 r;
  r[0] = (bf16_t)a[0]; r[1] = (bf16_t)a[1]; r[2] = (bf16_t)a[2]; r[3] = (bf16_t)a[3];
  r[4] = (bf16_t)b[0]; r[5] = (bf16_t)b[1]; r[6] = (bf16_t)b[2]; r[7] = (bf16_t)b[3];
  return r;
}

// f32-vs-bf16 sniffer on w_q's first 64 uint16s (validated: picks f32 path).
__global__ void detect_dtype(const unsigned short* __restrict__ w,
                             int* __restrict__ flag) {
  const unsigned short u = w[threadIdx.x];
  const bool big = (u & 0x7F80u) >= 0x3F80u;
  const unsigned long long m = __ballot(big);
  if (threadIdx.x == 0) *flag = (m != 0ull) ? 1 : 0;
}

// ---------------------------------------------------------------------------
// C[M,1024] = A[M,1024] @ W[1024,1024]^T, row-major, OutT out (bf16 or f32).
// Tile 128x128, BK=32, 4 waves (2x2), 4x4 mfma_16x16x32 per wave.
// LDS stride 40 (16B-aligned rows, <=2-way bank aliasing = free).   [R5 green]
// Double-buffered LDS + register prefetch (R8).
// ---------------------------------------------------------------------------
template <bool AF32, bool WF32, typename OutT>
static __device__ __forceinline__
void gemm_core(const void* __restrict__ Av, const void* __restrict__ Wv,
               OutT* __restrict__ C, bf16_t* sA, bf16_t* sB)
{
  const int K = 1024;
  const int tid  = threadIdx.x;
  const int wave = tid >> 6;
  const int lane = tid & 63;
  const int wm = wave >> 1, wn = wave & 1;
  const int bm = blockIdx.y * 128, bn = blockIdx.x * 128;
  const int quad = lane >> 4, r16 = lane & 15;

  floatx4 acc[4][4];
  #pragma unroll
  for (int i = 0; i < 4; ++i)
    #pragma unroll
    for (int j = 0; j < 4; ++j) acc[i][j] = {0.f, 0.f, 0.f, 0.f};

  const int srow = tid >> 2;       // 0..63
  const int scol = (tid & 3) * 8;  // 0,8,16,24
  const size_t a0 = (size_t)(bm + srow) * K + scol;
  const size_t a1 = a0 + (size_t)64 * K;
  const size_t w0 = (size_t)(bn + srow) * K + scol;
  const size_t w1 = w0 + (size_t)64 * K;

  // staging registers (raw as loaded; cvt deferred to LDS-write time)
  floatx4 fa[2][2], fw[2][2];
  bf16x8  ba[2],  bw[2];

  auto stage_load = [&](int k0) {
    if constexpr (AF32) {
      const float* Af = (const float*)Av;
      fa[0][0] = *(const floatx4*)(Af + a0 + k0);
      fa[0][1] = *(const floatx4*)(Af + a0 + k0 + 4);
      fa[1][0] = *(const floatx4*)(Af + a1 + k0);
      fa[1][1] = *(const floatx4*)(Af + a1 + k0 + 4);
    } else {
      const bf16_t* Ab = (const bf16_t*)Av;
      ba[0] = *(const bf16x8*)(Ab + a0 + k0);
      ba[1] = *(const bf16x8*)(Ab + a1 + k0);
    }
    if constexpr (WF32) {
      const float* Wf = (const float*)Wv;
      fw[0][0] = *(const floatx4*)(Wf + w0 + k0);
      fw[0][1] = *(const floatx4*)(Wf + w0 + k0 + 4);
      fw[1][0] = *(const floatx4*)(Wf + w1 + k0);
      fw[1][1] = *(const floatx4*)(Wf + w1 + k0 + 4);
    } else {
      const bf16_t* Wb = (const bf16_t*)Wv;
      bw[0] = *(const bf16x8*)(Wb + w0 + k0);
      bw[1] = *(const bf16x8*)(Wb + w1 + k0);
    }
  };

  stage_load(0);

  int buf = 0;
  for (int k0 = 0; k0 < K; k0 += 32) {
    bf16_t* cA = sA + buf * (128 * 40);
    bf16_t* cB = sB + buf * (128 * 40);
    {
      bf16x8 va0, va1, vb0, vb1;
      if constexpr (AF32) {
        va0 = cvt8p(fa[0][0], fa[0][1]);
        va1 = cvt8p(fa[1][0], fa[1][1]);
      } else {
        va0 = ba[0]; va1 = ba[1];
      }
      if constexpr (WF32) {
        vb0 = cvt8p(fw[0][0], fw[0][1]);
        vb1 = cvt8p(fw[1][0], fw[1][1]);
      } else {
        vb0 = bw[0]; vb1 = bw[1];
      }
      *(bf16x8*)&cA[srow * 40 + scol]        = va0;
      *(bf16x8*)&cA[(srow + 64) * 40 + scol] = va1;
      *(bf16x8*)&cB[srow * 40 + scol]        = vb0;
      *(bf16x8*)&cB[(srow + 64) * 40 + scol] = vb1;
    }
    __syncthreads();

    // prefetch next k-tile AFTER the barrier; latency hides under the MFMAs
    if (k0 + 32 < K) stage_load(k0 + 32);

    bf16x8 af[4], bv[4];
    #pragma unroll
    for (int mi = 0; mi < 4; ++mi)
      af[mi] = *(const bf16x8*)&cA[(wm * 64 + mi * 16 + r16) * 40 + quad * 8];
    #pragma unroll
    for (int ni = 0; ni < 4; ++ni)
      bv[ni] = *(const bf16x8*)&cB[(wn * 64 + ni * 16 + r16) * 40 + quad * 8];
    #pragma unroll
    for (int mi = 0; mi < 4; ++mi)
      #pragma unroll
      for (int ni = 0; ni < 4; ++ni)
        acc[mi][ni] = MFMA(af[mi], bv[ni], acc[mi][ni]);

    buf ^= 1;  // next write goes to the other buffer; no second barrier needed
  }

  #pragma unroll
  for (int mi = 0; mi < 4; ++mi)
    #pragma unroll
    for (int ni = 0; ni < 4; ++ni)
      #pragma unroll
      for (int r = 0; r < 4; ++r) {
        const int row = bm + wm * 64 + mi * 16 + quad * 4 + r;
        const int col = bn + wn * 64 + ni * 16 + r16;
        C[(size_t)row * 1024 + col] = (OutT)acc[mi][ni][r];
      }
}

// ADT: 0 = A external (f32/bf16 per flag), 1 = A internal bf16.
template <int ADT, typename OutT>
__global__ __launch_bounds__(256, 2)
void gemm_bt(const void* __restrict__ Av, const void* __restrict__ Wv,
             OutT* __restrict__ C, const int* __restrict__ flag)
{
  __shared__ __align__(16) bf16_t sA[2 * 128 * 40];  // 20 KB
  __shared__ __align__(16) bf16_t sB[2 * 128 * 40];  // 20 KB
  const int f32in = *flag;
  if (ADT == 0) {
    if (f32in) gemm_core<true,  true >(Av, Wv, C, sA, sB);
    else       gemm_core<false, false>(Av, Wv, C, sA, sB);
  } else {
    if (f32in) gemm_core<false, true >(Av, Wv, C, sA, sB);
    else       gemm_core<false, false>(Av, Wv, C, sA, sB);
  }
}

// ---------------------------------------------------------------------------
// Causal MFMA flash attention over row-major [8192][1024] bf16 q/k/v, head =
// 64-col slice. Block = 256 threads (4 waves): one (bh, 64-row q-tile).
// Wave w owns S/O rows [w*16, w*16+16). BKV = 64. Finite mask sentinels.
// All LDS tiles [64][64] XOR-swizzled: idx = row*64 + (col ^ ((row&7)<<3)),
// applied identically on write and read -> ds_read_b128 conflict-free.
// Next K/V tile prefetched into regs after the stage barrier (T14).
// Output in-place over q rows (block-private).        [R7: 305 -> 217 us]
// ---------------------------------------------------------------------------
__global__ __launch_bounds__(256, 4)
void flash_attn(bf16_t* qio, const bf16_t* __restrict__ kh,
                const bf16_t* __restrict__ vh)
{
  __shared__ __align__(16) bf16_t sK[64 * 64];    // [kv][d]  8 KB, swizzled
  __shared__ __align__(16) bf16_t sVt[64 * 64];   // [d][kv]  8 KB, swizzled
  __shared__ __align__(16) bf16_t sP[64 * 64];    // [q][kv]  8 KB, swizzled
  const int tid  = threadIdx.x;
  const int wave = tid >> 6;
  const int lane = tid & 63;
  const int quad = lane >> 4, r16 = lane & 15;
  const int b = blockIdx.x >> 4, h = blockIdx.x & 15;
  const int q0 = (int)(gridDim.y - 1 - blockIdx.y) * 64;  // heavy tiles first
  const size_t hb = ((size_t)b * 2048) * 1024 + (size_t)h * 64;
  const int swl = (r16 & 7) << 3;  // read-side XOR for r16-indexed rows

  // Q fragments (reused across all kv tiles): rows q0 + wave*16 + r16
  bf16x8 qf[2];
  #pragma unroll
  for (int ks = 0; ks < 2; ++ks)
    qf[ks] = *(const bf16x8*)(qio + hb +
        (size_t)(q0 + wave * 16 + r16) * 1024 + ks * 32 + quad * 8);

  floatx4 o[4];
  float mrow[4], lrow[4];
  #pragma unroll
  for (int nd = 0; nd < 4; ++nd) o[nd] = {0.f, 0.f, 0.f, 0.f};
  #pragma unroll
  for (int r = 0; r < 4; ++r) { mrow[r] = NEG_BIG; lrow[r] = 0.f; }

  const float sc = 0.125f * 1.44269504089f;  // 1/sqrt(64) * log2(e)
  const int kend = q0 + 64;

  // staging decomposition (per thread, per j): K chunk (row c>>3, col (c&7)*8)
  // and V chunk (row c&63, col (c>>6)*8), c = j*256 + tid.
  bf16x8 kst[2], vst[2];
  #pragma unroll
  for (int j = 0; j < 2; ++j) {
    const int c = j * 256 + tid;
    kst[j] = *(const bf16x8*)(kh + hb + (size_t)(c >> 3) * 1024 + (c & 7) * 8);
    vst[j] = *(const bf16x8*)(vh + hb + (size_t)(c & 63) * 1024 + (c >> 6) * 8);
  }

  for (int kv0 = 0; kv0 < kend; kv0 += 64) {
    // ---- write staged regs -> LDS (swizzled) ----
    #pragma unroll
    for (int j = 0; j < 2; ++j) {
      const int c = j * 256 + tid;
      const int krow = c >> 3, kcol = (c & 7) * 8;
      *(bf16x8*)&sK[krow * 64 + (kcol ^ ((krow & 7) << 3))] = kst[j];
      const int vkv = c & 63, vd = (c >> 6) * 8;
      #pragma unroll
      for (int e = 0; e < 8; ++e)        // row = vd+e, (row&7)==e since vd%8==0
        sVt[(vd + e) * 64 + (vkv ^ (e << 3))] = vst[j][e];
    }
    __syncthreads();

    // ---- prefetch next tile into regs; latency hides under QK/softmax/PV ----
    if (kv0 + 64 < kend) {
      #pragma unroll
      for (int j = 0; j < 2; ++j) {
        const int c = j * 256 + tid;
        kst[j] = *(const bf16x8*)(kh + hb + (size_t)(kv0 + 64 + (c >> 3)) * 1024 + (c & 7) * 8);
        vst[j] = *(const bf16x8*)(vh + hb + (size_t)(kv0 + 64 + (c & 63)) * 1024 + (c >> 6) * 8);
      }
    }

    // ---- S = Q K^T ----
    floatx4 s[4];
    #pragma unroll
    for (int nk = 0; nk < 4; ++nk) s[nk] = {0.f, 0.f, 0.f, 0.f};
    #pragma unroll
    for (int ks = 0; ks < 2; ++ks) {
      bf16x8 bk[4];
      #pragma unroll
      for (int nk = 0; nk < 4; ++nk)
        bk[nk] = *(const bf16x8*)&sK[(nk * 16 + r16) * 64 + ((ks * 32 + quad * 8) ^ swl)];
      #pragma unroll
      for (int nk = 0; nk < 4; ++nk)
        s[nk] = MFMA(qf[ks], bk[nk], s[nk]);
    }

    // ---- scale + causal mask (exp2 domain, finite sentinel) ----
    const int rowb = q0 + wave * 16 + quad * 4;
    const bool domask = (kv0 + 63 > rowb);
    #pragma unroll
    for (int nk = 0; nk < 4; ++nk) {
      const int col = kv0 + nk * 16 + r16;
      #pragma unroll
      for (int r = 0; r < 4; ++r) {
        float t = s[nk][r] * sc;
        if (domask && col > rowb + r) t = NEG_BIG;
        s[nk][r] = t;
      }
    }

    // ---- online softmax; P -> LDS in A-operand layout (swizzled) ----
    #pragma unroll
    for (int r = 0; r < 4; ++r) {
      float mx = fmaxf(fmaxf(s[0][r], s[1][r]), fmaxf(s[2][r], s[3][r]));
      #pragma unroll
      for (int off = 8; off >= 1; off >>= 1)
        mx = fmaxf(mx, __shfl_xor(mx, off, 64));
      const float mnew  = fmaxf(mrow[r], mx);
      const float alpha = exp2f(mrow[r] - mnew);
      mrow[r] = mnew;
      float ls = 0.f;
      const int prow = wave * 16 + quad * 4 + r;
      const int psw  = (prow & 7) << 3;
      #pragma unroll
      for (int nk = 0; nk < 4; ++nk) {
        const bf16_t pb = f2bf(exp2f(s[nk][r] - mnew));
        ls += (float)pb;  // denominator matches the bf16 P used in PV
        sP[prow * 64 + ((nk * 16 + r16) ^ psw)] = pb;
      }
      #pragma unroll
      for (int off = 8; off >= 1; off >>= 1)
        ls += __shfl_xor(ls, off, 64);
      lrow[r] = lrow[r] * alpha + ls;
      #pragma unroll
      for (int nd = 0; nd < 4; ++nd) o[nd][r] *= alpha;
    }
    __syncthreads();  // sP visible across lanes

    // ---- O += P V ----
    #pragma unroll
    for (int ks = 0; ks < 2; ++ks) {
      const int cb = (ks * 32 + quad * 8) ^ swl;
      const bf16x8 pa = *(const bf16x8*)&sP[(wave * 16 + r16) * 64 + cb];
      bf16x8 vb[4];
      #pragma unroll
      for (int nd = 0; nd < 4; ++nd)
        vb[nd] = *(const bf16x8*)&sVt[(nd * 16 + r16) * 64 + cb];
      #pragma unroll
      for (int nd = 0; nd < 4; ++nd)
        o[nd] = MFMA(pa, vb[nd], o[nd]);
    }
    __syncthreads();  // protect sK/sVt/sP for next iteration
  }

  // ---- normalize + store (in-place over q rows; block-private) ----
  #pragma unroll
  for (int r = 0; r < 4; ++r) {
    const float inv = 1.f / lrow[r];
    const int row = q0 + wave * 16 + quad * 4 + r;
    #pragma unroll
    for (int nd = 0; nd < 4; ++nd)
      qio[hb + (size_t)row * 1024 + nd * 16 + r16] = f2bf(o[nd][r] * inv);
  }
}

// ---------------------------------------------------------------------------
extern "C" void kernel_launch(void* const* d_in, const int* in_sizes, int n_in,
                              void* d_out, int out_size, void* d_ws, size_t ws_size,
                              hipStream_t stream) {
  (void)in_sizes; (void)n_in; (void)out_size; (void)ws_size;
  const size_t TSZ = (size_t)8192 * 1024;
  int*    flag = (int*)d_ws;
  bf16_t* qws  = (bf16_t*)((char*)d_ws + 16);
  bf16_t* kws  = qws + TSZ;
  bf16_t* vws  = (bf16_t*)d_out;  // bf16 v parked in f32 out buffer

  detect_dtype<<<1, 64, 0, stream>>>((const unsigned short*)d_in[3], flag);

  const dim3 gg(8, 64);  // (N/128, M/128)
  gemm_bt<0, bf16_t><<<gg, 256, 0, stream>>>(d_in[0], d_in[3], qws, flag);
  gemm_bt<0, bf16_t><<<gg, 256, 0, stream>>>(d_in[1], d_in[4], kws, flag);
  gemm_bt<0, bf16_t><<<gg, 256, 0, stream>>>(d_in[2], d_in[5], vws, flag);
  flash_attn<<<dim3(64, 32), 256, 0, stream>>>(qws, kws, vws);
  gemm_bt<1, float><<<gg, 256, 0, stream>>>(qws, d_in[6], (float*)d_out, flag);
}